// Round 2
// baseline (329.209 us; speedup 1.0000x reference)
//
#include <hip/hip_runtime.h>

#define BATCH 2
#define HEADS 16
#define SEQ 2048
#define HW 64
#define DMODEL 1024

typedef unsigned short u16;
typedef __attribute__((ext_vector_type(4))) unsigned short u16x4;
typedef __attribute__((ext_vector_type(8))) short short8;
typedef __attribute__((ext_vector_type(4))) float floatx4;

__device__ __forceinline__ u16 f2bf(float f) {
    union { float f; unsigned int u; } v; v.f = f;
    unsigned int r = v.u + 0x7fffu + ((v.u >> 16) & 1u);
    return (u16)(r >> 16);
}

// C = X[M,K] @ W[N,K]^T for K and V only, output bf16 per-head layout [B][H][S][64].
// grid (8, 32, 2), block 256. blockIdx.z: 0=K, 1=V.
__global__ __launch_bounds__(256) void proj_kernel(
    const float* __restrict__ Xk, const float* __restrict__ Xv,
    const float* __restrict__ Wk, const float* __restrict__ Wv,
    u16* __restrict__ Ok, u16* __restrict__ Ov)
{
    const float* X; const float* W; u16* out;
    if (blockIdx.z == 0) { X = Xk; W = Wk; out = Ok; }
    else                 { X = Xv; W = Wv; out = Ov; }

    __shared__ u16 As[128][72];   // +8 pad breaks pow-2 stride for b128 frag reads
    __shared__ u16 Bs[128][72];

    const int tid = threadIdx.x;
    const int lane = tid & 63, wave = tid >> 6;
    const int quad = lane >> 4, l15 = lane & 15;
    const int wm = (wave >> 1) << 6, wn = (wave & 1) << 6;
    const int tm = blockIdx.y, tn = blockIdx.x;

    floatx4 acc[4][4];
    for (int i = 0; i < 4; i++) for (int j = 0; j < 4; j++) acc[i][j] = (floatx4)0.0f;

    for (int k0 = 0; k0 < DMODEL; k0 += 64) {
        for (int i = 0; i < 8; i++) {
            int id = tid + (i << 8);
            int r = id >> 4, c4 = (id & 15) << 2;
            float4 a = *reinterpret_cast<const float4*>(X + (size_t)(tm * 128 + r) * DMODEL + k0 + c4);
            u16x4 pa; pa.x = f2bf(a.x); pa.y = f2bf(a.y); pa.z = f2bf(a.z); pa.w = f2bf(a.w);
            *reinterpret_cast<u16x4*>(&As[r][c4]) = pa;
            float4 b = *reinterpret_cast<const float4*>(W + (size_t)(tn * 128 + r) * DMODEL + k0 + c4);
            u16x4 pb; pb.x = f2bf(b.x); pb.y = f2bf(b.y); pb.z = f2bf(b.z); pb.w = f2bf(b.w);
            *reinterpret_cast<u16x4*>(&Bs[r][c4]) = pb;
        }
        __syncthreads();
        for (int kc = 0; kc < 2; kc++) {
            short8 af[4], bf[4];
            for (int i = 0; i < 4; i++)
                af[i] = *reinterpret_cast<const short8*>(&As[wm + i * 16 + l15][kc * 32 + quad * 8]);
            for (int j = 0; j < 4; j++)
                bf[j] = *reinterpret_cast<const short8*>(&Bs[wn + j * 16 + l15][kc * 32 + quad * 8]);
            for (int i = 0; i < 4; i++)
                for (int j = 0; j < 4; j++)
                    acc[i][j] = __builtin_amdgcn_mfma_f32_16x16x32_bf16(af[i], bf[j], acc[i][j], 0, 0, 0);
        }
        __syncthreads();
    }

    for (int i = 0; i < 4; i++) for (int j = 0; j < 4; j++) {
        int n = (tn << 7) + wn + (j << 4) + l15;
        int h = n >> 6, d = n & 63;
        for (int r = 0; r < 4; r++) {
            int m = (tm << 7) + wm + (i << 4) + (quad << 2) + r;
            int b = m >> 11, s = m & 2047;
            out[(size_t)((((b << 4) + h) << 11) + s) * 64 + d] = f2bf(acc[i][j][r]);
        }
    }
}

// Flash attention, Q-projection fused into prologue. grid 1024, block 256 (4 waves).
// LDS aliased: prologue {Xs,Ws,Qs} reuse main-loop {Ks,Vt,Ps} regions.
__global__ __launch_bounds__(256) void attn_kernel(
    const float* __restrict__ Xq, const float* __restrict__ Wq,
    const u16* __restrict__ K, const u16* __restrict__ V,
    float* __restrict__ out)
{
    __shared__ u16 smem[3][64][72];

    const int tid = threadIdx.x;
    const int lane = tid & 63, wave = tid >> 6;
    const int quad = lane >> 4, l15 = lane & 15;

    const int bid = blockIdx.x;
    const int qt = 31 - (bid >> 5);      // heavy q-tiles dispatch first
    const int bh = bid & 31;
    const int b = bh >> 4, h = bh & 15;
    const float slope = exp2f(-0.5f * (float)(h + 1));
    const int q0 = qt << 6;

    const u16* Kh = K + (size_t)bh * SEQ * HW;
    const u16* Vh = V + (size_t)bh * SEQ * HW;

    // ---- prologue: Q tile = X[b, q0:q0+64, :] @ Wq[h*64:h*64+64, :]^T ----
    {
        const float* Xb = Xq + (size_t)b * SEQ * DMODEL;
        const float* Wh = Wq + (size_t)h * 64 * DMODEL;
        floatx4 accq[4];
        for (int t = 0; t < 4; t++) accq[t] = (floatx4)0.0f;

        for (int k0 = 0; k0 < DMODEL; k0 += 64) {
            for (int i = 0; i < 4; i++) {
                int id = tid + (i << 8);          // 0..1023
                int r = id >> 4, c4 = (id & 15) << 2;
                float4 a = *reinterpret_cast<const float4*>(Xb + (size_t)(q0 + r) * DMODEL + k0 + c4);
                u16x4 pa; pa.x = f2bf(a.x); pa.y = f2bf(a.y); pa.z = f2bf(a.z); pa.w = f2bf(a.w);
                *reinterpret_cast<u16x4*>(&smem[0][r][c4]) = pa;
                float4 w = *reinterpret_cast<const float4*>(Wh + (size_t)r * DMODEL + k0 + c4);
                u16x4 pw; pw.x = f2bf(w.x); pw.y = f2bf(w.y); pw.z = f2bf(w.z); pw.w = f2bf(w.w);
                *reinterpret_cast<u16x4*>(&smem[1][r][c4]) = pw;
            }
            __syncthreads();
            for (int kc = 0; kc < 2; kc++) {
                short8 xa = *reinterpret_cast<const short8*>(&smem[0][wave * 16 + l15][kc * 32 + quad * 8]);
                for (int tn = 0; tn < 4; tn++) {
                    short8 wb = *reinterpret_cast<const short8*>(&smem[1][tn * 16 + l15][kc * 32 + quad * 8]);
                    accq[tn] = __builtin_amdgcn_mfma_f32_16x16x32_bf16(xa, wb, accq[tn], 0, 0, 0);
                }
            }
            __syncthreads();
        }
        // C-layout -> LDS (bf16) so we can re-read in A-operand layout
        for (int tn = 0; tn < 4; tn++)
            for (int r = 0; r < 4; r++)
                smem[2][wave * 16 + (quad << 2) + r][tn * 16 + l15] = f2bf(accq[tn][r]);
    }
    // per-wave in-order LDS: write then read of wave-private rows needs no barrier
    short8 qf[2];
    qf[0] = *reinterpret_cast<const short8*>(&smem[2][wave * 16 + l15][quad * 8]);
    qf[1] = *reinterpret_cast<const short8*>(&smem[2][wave * 16 + l15][32 + quad * 8]);
    __syncthreads();

    float m_run[4], l_run[4];
    floatx4 acc_o[4];
    for (int r = 0; r < 4; r++) { m_run[r] = -1e30f; l_run[r] = 0.0f; }
    for (int t = 0; t < 4; t++) acc_o[t] = (floatx4)0.0f;

    const float LOG2E = 1.44269504088896340736f;
    const float scale = 0.125f;   // 1/sqrt(64)

    u16 (*Ks)[72] = smem[0];
    u16 (*Vt)[72] = smem[1];
    u16 (*Ps)[72] = &smem[2][wave * 16];   // wave-private 16x72

    for (int kt = 0; kt <= qt; kt++) {
        const int kv0 = kt << 6;
        for (int i = 0; i < 2; i++) {
            int id = tid + (i << 8);
            int r = id >> 3, c8 = (id & 7) << 3;
            *reinterpret_cast<short8*>(&Ks[r][c8]) =
                *reinterpret_cast<const short8*>(Kh + (size_t)(kv0 + r) * 64 + c8);
        }
        for (int i = 0; i < 16; i++) {
            int id = tid + (i << 8);
            int j = id >> 6, d = id & 63;
            Vt[d][j] = Vh[(size_t)(kv0 + j) * 64 + d];
        }
        __syncthreads();

        floatx4 sv[4];
        for (int tn = 0; tn < 4; tn++) {
            floatx4 s = (floatx4)0.0f;
            short8 kf0 = *reinterpret_cast<const short8*>(&Ks[tn * 16 + l15][quad * 8]);
            short8 kf1 = *reinterpret_cast<const short8*>(&Ks[tn * 16 + l15][32 + quad * 8]);
            s = __builtin_amdgcn_mfma_f32_16x16x32_bf16(qf[0], kf0, s, 0, 0, 0);
            s = __builtin_amdgcn_mfma_f32_16x16x32_bf16(qf[1], kf1, s, 0, 0, 0);
            sv[tn] = s;
        }

        const int row_g = q0 + (wave << 4) + (quad << 2);
        for (int tn = 0; tn < 4; tn++) {
            int col_g = kv0 + tn * 16 + l15;
            for (int r = 0; r < 4; r++) {
                int i_g = row_g + r;
                float sc = sv[tn][r] * scale + slope * (float)(col_g - i_g);
                if (col_g > i_g) sc = -1e9f;
                sv[tn][r] = sc;
            }
        }

        float mx[4];
        for (int r = 0; r < 4; r++)
            mx[r] = fmaxf(fmaxf(sv[0][r], sv[1][r]), fmaxf(sv[2][r], sv[3][r]));
        for (int off = 1; off < 16; off <<= 1)
            for (int r = 0; r < 4; r++)
                mx[r] = fmaxf(mx[r], __shfl_xor(mx[r], off));

        float rs[4];
        for (int r = 0; r < 4; r++) {
            float mnew = fmaxf(m_run[r], mx[r]);
            float alpha = exp2f((m_run[r] - mnew) * LOG2E);
            m_run[r] = mnew;
            l_run[r] *= alpha;
            acc_o[0][r] *= alpha; acc_o[1][r] *= alpha;
            acc_o[2][r] *= alpha; acc_o[3][r] *= alpha;
            rs[r] = 0.0f;
        }
        for (int tn = 0; tn < 4; tn++)
            for (int r = 0; r < 4; r++) {
                float p = exp2f((sv[tn][r] - m_run[r]) * LOG2E);
                sv[tn][r] = p;
                rs[r] += p;
                Ps[(quad << 2) + r][tn * 16 + l15] = f2bf(p);
            }
        for (int off = 1; off < 16; off <<= 1)
            for (int r = 0; r < 4; r++)
                rs[r] += __shfl_xor(rs[r], off);
        for (int r = 0; r < 4; r++) l_run[r] += rs[r];

        for (int c = 0; c < 2; c++) {
            short8 pf = *reinterpret_cast<const short8*>(&Ps[l15][c * 32 + quad * 8]);
            for (int t2 = 0; t2 < 4; t2++) {
                short8 vf = *reinterpret_cast<const short8*>(&Vt[t2 * 16 + l15][c * 32 + quad * 8]);
                acc_o[t2] = __builtin_amdgcn_mfma_f32_16x16x32_bf16(pf, vf, acc_o[t2], 0, 0, 0);
            }
        }
        __syncthreads();
    }

    float inv[4];
    for (int r = 0; r < 4; r++) inv[r] = 1.0f / l_run[r];
    const int orow = q0 + (wave << 4) + (quad << 2);
    for (int t2 = 0; t2 < 4; t2++) {
        int d = t2 * 16 + l15;
        for (int r = 0; r < 4; r++)
            out[(size_t)(b * SEQ + orow + r) * DMODEL + h * 64 + d] = acc_o[t2][r] * inv[r];
    }
}

extern "C" void kernel_launch(void* const* d_in, const int* in_sizes, int n_in,
                              void* d_out, int out_size, void* d_ws, size_t ws_size,
                              hipStream_t stream) {
    const float* q  = (const float*)d_in[0];
    const float* k  = (const float*)d_in[1];
    const float* v  = (const float*)d_in[2];
    // d_in[3] = causal mask: recomputed analytically in-kernel
    const float* wq = (const float*)d_in[4];
    const float* wk = (const float*)d_in[5];
    const float* wv = (const float*)d_in[6];
    float* out = (float*)d_out;

    const size_t headElems = (size_t)BATCH * HEADS * SEQ * HW;  // 4,194,304
    u16* Kb = (u16*)d_ws;
    u16* Vb = Kb + headElems;   // 16 MB total workspace (fits ws_size == out bytes)

    dim3 pgrid(DMODEL / 128, (BATCH * SEQ) / 128, 2);
    proj_kernel<<<pgrid, 256, 0, stream>>>(k, v, wk, wv, Kb, Vb);
    attn_kernel<<<BATCH * HEADS * (SEQ / 64), 256, 0, stream>>>(q, wq, Kb, Vb, out);
}

// Round 3
// 281.044 us; speedup vs baseline: 1.1714x; 1.1714x over previous
//
#include <hip/hip_runtime.h>

#define BATCH 2
#define HEADS 16
#define SEQ 2048
#define HW 64
#define DMODEL 1024

typedef unsigned short u16;
typedef __attribute__((ext_vector_type(4))) unsigned short u16x4;
typedef __attribute__((ext_vector_type(8))) short short8;
typedef __attribute__((ext_vector_type(4))) float floatx4;

__device__ __forceinline__ u16 f2bf(float f) {
    union { float f; unsigned int u; } v; v.f = f;
    unsigned int r = v.u + 0x7fffu + ((v.u >> 16) & 1u);
    return (u16)(r >> 16);
}

// K: out row-major per head [bh][s][64]. V: out TRANSPOSED per head [bh][d][s].
// grid (8, 32, 2), block 256. blockIdx.z: 0=K, 1=V.
__global__ __launch_bounds__(256) void proj_kernel(
    const float* __restrict__ Xk, const float* __restrict__ Xv,
    const float* __restrict__ Wk, const float* __restrict__ Wv,
    u16* __restrict__ Ok, u16* __restrict__ Ov)
{
    const float* X; const float* W;
    if (blockIdx.z == 0) { X = Xk; W = Wk; }
    else                 { X = Xv; W = Wv; }

    __shared__ u16 As[128][72];
    __shared__ u16 Bs[128][72];

    const int tid = threadIdx.x;
    const int lane = tid & 63, wave = tid >> 6;
    const int quad = lane >> 4, l15 = lane & 15;
    const int wm = (wave >> 1) << 6, wn = (wave & 1) << 6;
    const int tm = blockIdx.y, tn = blockIdx.x;

    floatx4 acc[4][4];
    for (int i = 0; i < 4; i++) for (int j = 0; j < 4; j++) acc[i][j] = (floatx4)0.0f;

    for (int k0 = 0; k0 < DMODEL; k0 += 64) {
        for (int i = 0; i < 8; i++) {
            int id = tid + (i << 8);
            int r = id >> 4, c4 = (id & 15) << 2;
            float4 a = *reinterpret_cast<const float4*>(X + (size_t)(tm * 128 + r) * DMODEL + k0 + c4);
            u16x4 pa; pa.x = f2bf(a.x); pa.y = f2bf(a.y); pa.z = f2bf(a.z); pa.w = f2bf(a.w);
            *reinterpret_cast<u16x4*>(&As[r][c4]) = pa;
            float4 b = *reinterpret_cast<const float4*>(W + (size_t)(tn * 128 + r) * DMODEL + k0 + c4);
            u16x4 pb; pb.x = f2bf(b.x); pb.y = f2bf(b.y); pb.z = f2bf(b.z); pb.w = f2bf(b.w);
            *reinterpret_cast<u16x4*>(&Bs[r][c4]) = pb;
        }
        __syncthreads();
        for (int kc = 0; kc < 2; kc++) {
            short8 af[4], bf[4];
            for (int i = 0; i < 4; i++)
                af[i] = *reinterpret_cast<const short8*>(&As[wm + i * 16 + l15][kc * 32 + quad * 8]);
            for (int j = 0; j < 4; j++)
                bf[j] = *reinterpret_cast<const short8*>(&Bs[wn + j * 16 + l15][kc * 32 + quad * 8]);
            for (int i = 0; i < 4; i++)
                for (int j = 0; j < 4; j++)
                    acc[i][j] = __builtin_amdgcn_mfma_f32_16x16x32_bf16(af[i], bf[j], acc[i][j], 0, 0, 0);
        }
        __syncthreads();
    }

    if (blockIdx.z == 0) {
        // K: [bh][s][64]
        for (int i = 0; i < 4; i++) for (int j = 0; j < 4; j++) {
            int n = (tn << 7) + wn + (j << 4) + l15;
            int h = n >> 6, d = n & 63;
            for (int r = 0; r < 4; r++) {
                int m = (tm << 7) + wm + (i << 4) + (quad << 2) + r;
                int b = m >> 11, s = m & 2047;
                Ok[(size_t)((((b << 4) + h) << 11) + s) * 64 + d] = f2bf(acc[i][j][r]);
            }
        }
    } else {
        // V transposed: [bh][d][s], r (=s) contiguous -> packed 8B stores
        for (int i = 0; i < 4; i++) for (int j = 0; j < 4; j++) {
            int n = (tn << 7) + wn + (j << 4) + l15;
            int h = n >> 6, d = n & 63;
            int m = (tm << 7) + wm + (i << 4) + (quad << 2);
            int b = m >> 11, s0 = m & 2047;
            u16x4 pk;
            pk.x = f2bf(acc[i][j][0]); pk.y = f2bf(acc[i][j][1]);
            pk.z = f2bf(acc[i][j][2]); pk.w = f2bf(acc[i][j][3]);
            *reinterpret_cast<u16x4*>(Ov + ((size_t)(((b << 4) + h) << 6) + d) * SEQ + s0) = pk;
        }
    }
}

// Flash attention on S^T = K Q^T. grid 1024, block 256 (4 waves, 16 q-rows each).
__global__ __launch_bounds__(256) void attn_kernel(
    const float* __restrict__ Xq, const float* __restrict__ Wq,
    const u16* __restrict__ K, const u16* __restrict__ VtG,
    float* __restrict__ out)
{
    __shared__ u16 smem[3][64][72];   // [0]=Ks, [1]=Vt, [2]=Pt (wave-private strips)

    const int tid = threadIdx.x;
    const int lane = tid & 63, wave = tid >> 6;
    const int quad = lane >> 4, l15 = lane & 15;

    const int bid = blockIdx.x;
    const int qt = 31 - (bid >> 5);      // heavy q-tiles dispatch first
    const int bh = bid & 31;
    const int b = bh >> 4, h = bh & 15;
    const float slope = exp2f(-0.5f * (float)(h + 1));
    const int q0 = qt << 6;

    const u16* Kh  = K   + (size_t)bh * SEQ * HW;
    const u16* Vth = VtG + (size_t)bh * HW * SEQ;

    // ---- prologue: Q tile = X[b, q0:q0+64, :] @ Wq[h*64:+64, :]^T, scale folded ----
    {
        const float* Xb = Xq + (size_t)b * SEQ * DMODEL;
        const float* Wh = Wq + (size_t)h * 64 * DMODEL;
        floatx4 accq[4];
        for (int t = 0; t < 4; t++) accq[t] = (floatx4)0.0f;

        for (int k0 = 0; k0 < DMODEL; k0 += 64) {
            for (int i = 0; i < 4; i++) {
                int id = tid + (i << 8);
                int r = id >> 4, c4 = (id & 15) << 2;
                float4 a = *reinterpret_cast<const float4*>(Xb + (size_t)(q0 + r) * DMODEL + k0 + c4);
                u16x4 pa; pa.x = f2bf(a.x); pa.y = f2bf(a.y); pa.z = f2bf(a.z); pa.w = f2bf(a.w);
                *reinterpret_cast<u16x4*>(&smem[0][r][c4]) = pa;
                float4 w = *reinterpret_cast<const float4*>(Wh + (size_t)r * DMODEL + k0 + c4);
                u16x4 pw; pw.x = f2bf(w.x); pw.y = f2bf(w.y); pw.z = f2bf(w.z); pw.w = f2bf(w.w);
                *reinterpret_cast<u16x4*>(&smem[1][r][c4]) = pw;
            }
            __syncthreads();
            for (int kc = 0; kc < 2; kc++) {
                short8 xa = *reinterpret_cast<const short8*>(&smem[0][wave * 16 + l15][kc * 32 + quad * 8]);
                for (int tn = 0; tn < 4; tn++) {
                    short8 wb = *reinterpret_cast<const short8*>(&smem[1][tn * 16 + l15][kc * 32 + quad * 8]);
                    accq[tn] = __builtin_amdgcn_mfma_f32_16x16x32_bf16(xa, wb, accq[tn], 0, 0, 0);
                }
            }
            __syncthreads();
        }
        // C-layout -> LDS (bf16, 1/sqrt(64) folded in exactly)
        for (int tn = 0; tn < 4; tn++)
            for (int r = 0; r < 4; r++)
                smem[2][wave * 16 + (quad << 2) + r][tn * 16 + l15] = f2bf(accq[tn][r] * 0.125f);
    }
    short8 qf[2];   // B-operand frags (wave-private rows; in-order LDS, no barrier)
    qf[0] = *reinterpret_cast<const short8*>(&smem[2][wave * 16 + l15][quad * 8]);
    qf[1] = *reinterpret_cast<const short8*>(&smem[2][wave * 16 + l15][32 + quad * 8]);
    __syncthreads();

    u16 (*Ks)[72] = smem[0];
    u16 (*Vt)[72] = smem[1];
    u16 (*Pt)[72] = &smem[2][wave * 16];   // wave-private 16x72: Pt[q_local][kv_local]

    const float LOG2E = 1.44269504088896340736f;
    const int qg = q0 + (wave << 4) + l15;         // this lane's q row (global)

    float m_run = -1e30f, l_run = 0.0f;
    floatx4 acc_o[4];
    for (int t = 0; t < 4; t++) acc_o[t] = (floatx4)0.0f;

    for (int kt = 0; kt <= qt; kt++) {
        const int kv0 = kt << 6;
        {   // stage K [64][64] and V^T [64][64], all coalesced short8
            int r = tid >> 3, c8 = (tid & 7) << 3;
            *reinterpret_cast<short8*>(&Ks[r][c8]) =
                *reinterpret_cast<const short8*>(Kh + (size_t)(kv0 + r) * 64 + c8);
            *reinterpret_cast<short8*>(&Ks[r + 32][c8]) =
                *reinterpret_cast<const short8*>(Kh + (size_t)(kv0 + r + 32) * 64 + c8);
            *reinterpret_cast<short8*>(&Vt[r][c8]) =
                *reinterpret_cast<const short8*>(Vth + (size_t)r * SEQ + kv0 + c8);
            *reinterpret_cast<short8*>(&Vt[r + 32][c8]) =
                *reinterpret_cast<const short8*>(Vth + (size_t)(r + 32) * SEQ + kv0 + c8);
        }
        __syncthreads();

        // S^T = K Q^T : C rows = kv (4 frags), col = q = l15
        floatx4 sv[4];
        for (int t = 0; t < 4; t++) {
            short8 kf0 = *reinterpret_cast<const short8*>(&Ks[t * 16 + l15][quad * 8]);
            short8 kf1 = *reinterpret_cast<const short8*>(&Ks[t * 16 + l15][32 + quad * 8]);
            floatx4 s = (floatx4)0.0f;
            s = __builtin_amdgcn_mfma_f32_16x16x32_bf16(kf0, qf[0], s, 0, 0, 0);
            s = __builtin_amdgcn_mfma_f32_16x16x32_bf16(kf1, qf[1], s, 0, 0, 0);
            sv[t] = s;
        }

        // ALiBi + causal: sc = min(s + slope*rel, s - 1e9*rel), rel = kv - q
        const float fbase = (float)(kv0 + (quad << 2) - qg);
        float mloc = -1e30f;
        for (int t = 0; t < 4; t++)
            for (int r = 0; r < 4; r++) {
                float rel = fbase + (float)(t * 16 + r);
                float sc = fminf(fmaf(slope, rel, sv[t][r]), fmaf(-1e9f, rel, sv[t][r]));
                sv[t][r] = sc;
                mloc = fmaxf(mloc, sc);
            }
        mloc = fmaxf(mloc, __shfl_xor(mloc, 16));
        mloc = fmaxf(mloc, __shfl_xor(mloc, 32));

        float mnew = fmaxf(m_run, mloc);
        float alpha = __builtin_amdgcn_exp2f((m_run - mnew) * LOG2E);
        m_run = mnew;
        const float mL = mnew * LOG2E;

        float rs = 0.0f;
        for (int t = 0; t < 4; t++) {
            u16x4 pk;
            for (int r = 0; r < 4; r++) {
                float p = __builtin_amdgcn_exp2f(fmaf(sv[t][r], LOG2E, -mL));
                rs += p;
                pk[r] = f2bf(p);
            }
            *reinterpret_cast<u16x4*>(&Pt[l15][t * 16 + (quad << 2)]) = pk;
        }
        rs += __shfl_xor(rs, 16);
        rs += __shfl_xor(rs, 32);
        l_run = l_run * alpha + rs;
        for (int t = 0; t < 4; t++)
            for (int r = 0; r < 4; r++) acc_o[t][r] *= alpha;

        // O^T += V^T P^T : A = V^T (m=d), B = P^T (n=q)
        for (int c = 0; c < 2; c++) {
            short8 pf = *reinterpret_cast<const short8*>(&Pt[l15][c * 32 + quad * 8]);
            for (int t2 = 0; t2 < 4; t2++) {
                short8 vf = *reinterpret_cast<const short8*>(&Vt[t2 * 16 + l15][c * 32 + quad * 8]);
                acc_o[t2] = __builtin_amdgcn_mfma_f32_16x16x32_bf16(vf, pf, acc_o[t2], 0, 0, 0);
            }
        }
        __syncthreads();
    }

    // epilogue: O^T rows = d = t2*16+quad*4+r (contiguous in r -> float4), col = q = l15
    const float inv = 1.0f / l_run;
    float* op = out + (size_t)(b * SEQ + qg) * DMODEL + h * 64;
    for (int t2 = 0; t2 < 4; t2++) {
        float4 o;
        o.x = acc_o[t2][0] * inv; o.y = acc_o[t2][1] * inv;
        o.z = acc_o[t2][2] * inv; o.w = acc_o[t2][3] * inv;
        *reinterpret_cast<float4*>(op + t2 * 16 + (quad << 2)) = o;
    }
}

extern "C" void kernel_launch(void* const* d_in, const int* in_sizes, int n_in,
                              void* d_out, int out_size, void* d_ws, size_t ws_size,
                              hipStream_t stream) {
    const float* q  = (const float*)d_in[0];
    const float* k  = (const float*)d_in[1];
    const float* v  = (const float*)d_in[2];
    // d_in[3] = causal mask: recomputed analytically in-kernel
    const float* wq = (const float*)d_in[4];
    const float* wk = (const float*)d_in[5];
    const float* wv = (const float*)d_in[6];
    float* out = (float*)d_out;

    const size_t headElems = (size_t)BATCH * HEADS * SEQ * HW;  // 4,194,304
    u16* Kb  = (u16*)d_ws;
    u16* VtB = Kb + headElems;   // 16 MB total workspace

    dim3 pgrid(DMODEL / 128, (BATCH * SEQ) / 128, 2);
    proj_kernel<<<pgrid, 256, 0, stream>>>(k, v, wk, wv, Kb, VtB);
    attn_kernel<<<BATCH * HEADS * (SEQ / 64), 256, 0, stream>>>(q, wq, Kb, VtB, out);
}